// Round 4
// baseline (500.249 us; speedup 1.0000x reference)
//
#include <hip/hip_runtime.h>
#include <hip/hip_bf16.h>
#include <math.h>

#define NB 8
#define BN_EPS 1e-5f
#define CEXP 0.04508422002778011f  // log2(e)/32

typedef __attribute__((ext_vector_type(4))) float f32x4;
typedef __attribute__((ext_vector_type(8))) short short8;

__device__ __forceinline__ float bf2f(ushort h) {
    union { unsigned u; float f; } v; v.u = ((unsigned)h) << 16;
    return v.f;
}
__device__ __forceinline__ ushort f2bfu(float f) {
    __hip_bfloat16 h = __float2bfloat16(f);
    union { __hip_bfloat16 h; ushort u; } c; c.h = h; return c.u;
}
__device__ __forceinline__ void gld16(const ushort* g, ushort* l) {
    __builtin_amdgcn_global_load_lds(
        (const __attribute__((address_space(1))) void*)g,
        (__attribute__((address_space(3))) void*)l, 16, 0, 0);
}

// ---------------- workspace layout (bytes) ----------------
#define O_WKQV   0u          // ushort[2048*128]
#define O_BKQV   524288u     // float[2048]
#define O_WFH    532480u     // ushort[1024*1024]
#define O_WFL    2629632u    // ushort[1024*1024]
#define O_BF     4726784u    // float[1024]
#define O_TOKT   4730880u    // ushort[8*1024*1024]  (reused as t2T_hi)
#define O_T2TL   21508096u   // ushort[8*1024*1024]
#define O_KT     38285312u   // ushort[8*16*1024*32]
#define O_QT     46673920u   // ushort[8*16*1024*32]
#define O_V      55062528u   // ushort[8*16*64*1024]

// ---------------- prep: fold BN (q also folded with log2e/32), cast to bf16 ----------------
__global__ void prep_all(
    const float* __restrict__ kw, const float* __restrict__ kb, const float* __restrict__ kg,
    const float* __restrict__ kbe, const float* __restrict__ km, const float* __restrict__ kv,
    const float* __restrict__ qw, const float* __restrict__ qb, const float* __restrict__ qg,
    const float* __restrict__ qbe, const float* __restrict__ qm, const float* __restrict__ qv,
    const float* __restrict__ vw, const float* __restrict__ vb, const float* __restrict__ vg,
    const float* __restrict__ vbe, const float* __restrict__ vm, const float* __restrict__ vv,
    const float* __restrict__ fw, const float* __restrict__ fb, const float* __restrict__ fg,
    const float* __restrict__ fbe, const float* __restrict__ fm, const float* __restrict__ fv,
    ushort* __restrict__ wkqv, float* __restrict__ bkqv,
    ushort* __restrict__ wfh, ushort* __restrict__ wfl, float* __restrict__ bff)
{
    int bid = blockIdx.x;
    int tid = threadIdx.x;
    if (bid < 1024) {
        int idx = bid * 256 + tid;       // 0 .. 2048*128-1
        int co = idx >> 7, ci = idx & 127;
        const float *w, *b, *g, *be, *m, *vr; int r; float sc = 1.0f;
        if (co < 512)       { w = kw; b = kb; g = kg; be = kbe; m = km; vr = kv; r = co; }
        else if (co < 1024) { w = qw; b = qb; g = qg; be = qbe; m = qm; vr = qv; r = co - 512; sc = CEXP; }
        else                { w = vw; b = vb; g = vg; be = vbe; m = vm; vr = vv; r = co - 1024; }
        float inv = g[r] * rsqrtf(vr[r] + BN_EPS) * sc;
        wkqv[idx] = f2bfu(w[r * 128 + ci] * inv);
        if (ci == 0) bkqv[co] = (b[r] - m[r]) * inv + be[r] * sc;
    } else {
        int idx = (bid - 1024) * 256 + tid;  // 0 .. 1024*1024-1
        int co = idx >> 10, ci = idx & 1023;
        float inv = fg[co] * rsqrtf(fv[co] + BN_EPS);
        float w = fw[idx] * inv;
        ushort hi = f2bfu(w);
        wfh[idx] = hi;
        wfl[idx] = f2bfu(w - bf2f(hi));
        if (ci == 0) bff[co] = (fb[co] - fm[co]) * inv + fbe[co];
    }
}

// ---------------- transpose tokens: f32 [n][c][l] -> bf16 [n][l][c] ----------------
__global__ __launch_bounds__(256) void transpose_tokens(
    const float* __restrict__ x, ushort* __restrict__ xt)
{
    __shared__ float Ts[64][68];
    const int l0 = blockIdx.x * 64, c0 = blockIdx.y * 64, n = blockIdx.z;
    const int tid = threadIdx.x;
    #pragma unroll
    for (int r = 0; r < 4; ++r) {
        int idx = tid + 256 * r;
        int ci = idx >> 4, li4 = (idx & 15) * 4;
        float4 v4 = *(const float4*)&x[((size_t)(n * 1024 + c0 + ci)) * 1024 + l0 + li4];
        *(float4*)&Ts[ci][li4] = v4;
    }
    __syncthreads();
    #pragma unroll
    for (int r = 0; r < 2; ++r) {
        int idx = tid + 256 * r;
        int lr = idx >> 3, oc = idx & 7;
        union { ushort u[8]; uint4 v; } pk;
        #pragma unroll
        for (int i = 0; i < 8; ++i) pk.u[i] = f2bfu(Ts[oc * 8 + i][lr]);
        *(uint4*)&xt[((size_t)(n * 1024 + l0 + lr)) * 1024 + c0 + oc * 8] = pk.v;
    }
}

// ---------------- conv_kqv: bf16 MFMA GEMM, gld16 staging, writes KT/QT + V ----------------
// grid (8 lblk, 32 coblk, NB), block 256 (4 waves 2x2). Tile 64co x 128l, K=128.
__global__ __launch_bounds__(256) void conv_kqv_mfma(
    const ushort* __restrict__ xt, const ushort* __restrict__ wq,
    const float* __restrict__ bq,
    ushort* __restrict__ KT, ushort* __restrict__ QT, ushort* __restrict__ V)
{
    __shared__ ushort Ws[64 * 128];   // [co][ci], 16 slots/row, phys slot = logical ^ (row&15)
    __shared__ ushort Xs[128 * 128];  // [l][ci]
    const int l0 = blockIdx.x * 128, co0 = blockIdx.y * 64, n = blockIdx.z;
    const int tid = threadIdx.x;
    const int wid = tid >> 6, ln = tid & 63, g = ln >> 4, ln15 = ln & 15;
    const int wm = wid >> 1, wn = wid & 1;

    int in_off;
    if (co0 < 512)       in_off = (co0 >> 6) << 7;
    else if (co0 < 1024) in_off = ((co0 - 512) >> 6) << 7;
    else                 in_off = ((co0 - 1024) >> 7) << 7;

    // W: 64 rows x 256B = 1024 granules -> 4 issues
    #pragma unroll
    for (int j = 0; j < 4; ++j) {
        int g16 = wid * 64 + ln + j * 256;
        int row = g16 >> 4, phys = g16 & 15;
        int logical = phys ^ (row & 15);
        gld16(wq + (size_t)(co0 + row) * 128 + logical * 8,
              &Ws[(j * 256 + wid * 64) * 8]);
    }
    // X: 128 rows x 256B = 2048 granules -> 8 issues
    #pragma unroll
    for (int j = 0; j < 8; ++j) {
        int g16 = wid * 64 + ln + j * 256;
        int row = g16 >> 4, phys = g16 & 15;
        int logical = phys ^ (row & 15);
        gld16(xt + ((size_t)(n * 1024 + l0 + row)) * 1024 + in_off + logical * 8,
              &Xs[(j * 256 + wid * 64) * 8]);
    }
    __syncthreads();

    f32x4 acc[2][4];
    #pragma unroll
    for (int mf = 0; mf < 2; ++mf)
        #pragma unroll
        for (int nf = 0; nf < 4; ++nf) acc[mf][nf] = (f32x4){0.f, 0.f, 0.f, 0.f};

    #pragma unroll
    for (int ks = 0; ks < 4; ++ks) {
        short8 a[2], b[4];
        #pragma unroll
        for (int mf = 0; mf < 2; ++mf) {
            int row = wm * 32 + mf * 16 + ln15;
            int slot = ks * 4 + g;
            a[mf] = *(const short8*)&Ws[row * 128 + ((slot ^ (row & 15)) << 3)];
        }
        #pragma unroll
        for (int nf = 0; nf < 4; ++nf) {
            int row = wn * 64 + nf * 16 + ln15;
            int slot = ks * 4 + g;
            b[nf] = *(const short8*)&Xs[row * 128 + ((slot ^ (row & 15)) << 3)];
        }
        #pragma unroll
        for (int mf = 0; mf < 2; ++mf)
            #pragma unroll
            for (int nf = 0; nf < 4; ++nf)
                acc[mf][nf] = __builtin_amdgcn_mfma_f32_16x16x32_bf16(a[mf], b[nf], acc[mf][nf], 0, 0, 0);
    }

    #pragma unroll
    for (int mf = 0; mf < 2; ++mf) {
        int m0 = wm * 32 + mf * 16 + g * 4;
        int co = co0 + m0;
        float bb[4];
        #pragma unroll
        for (int r = 0; r < 4; ++r) bb[r] = bq[co + r];
        #pragma unroll
        for (int nf = 0; nf < 4; ++nf) {
            int l = l0 + wn * 64 + nf * 16 + ln15;
            float v0 = acc[mf][nf][0] + bb[0];
            float v1 = acc[mf][nf][1] + bb[1];
            float v2 = acc[mf][nf][2] + bb[2];
            float v3 = acc[mf][nf][3] + bb[3];
            if (co0 < 512) {
                int h = co >> 5, d = m0 & 31;
                union { ushort u[4]; uint2 v; } pk;
                pk.u[0] = f2bfu(v0); pk.u[1] = f2bfu(v1); pk.u[2] = f2bfu(v2); pk.u[3] = f2bfu(v3);
                *(uint2*)&KT[(((size_t)(n * 16 + h)) * 1024 + l) * 32 + d] = pk.v;
            } else if (co0 < 1024) {
                int cq = co - 512; int h = cq >> 5, d = m0 & 31;
                union { ushort u[4]; uint2 v; } pk;
                pk.u[0] = f2bfu(v0); pk.u[1] = f2bfu(v1); pk.u[2] = f2bfu(v2); pk.u[3] = f2bfu(v3);
                *(uint2*)&QT[(((size_t)(n * 16 + h)) * 1024 + l) * 32 + d] = pk.v;
            } else {
                int cv = co - 1024; int h = cv >> 6, dv = cv & 63;
                size_t base = (((size_t)(n * 16 + h)) * 64 + dv) * 1024 + l;
                V[base]          = f2bfu(v0);
                V[base + 1024]   = f2bfu(v1);
                V[base + 2048]   = f2bfu(v2);
                V[base + 3072]   = f2bfu(v3);
            }
        }
    }
}

// ---------------- attention: 64 q/wave, LDS K/V dbuf, no-max softmax, MFMA ----------------
// grid (4 qblk, 16 h, NB), block 256 (4 waves). Wave owns 64 q; block 256 q.
// LDS: Vs 16K + Ks 8K + Pt 32K = 56K -> 2 blocks/CU.
__global__ __launch_bounds__(256, 2) void attn_mfma(
    const ushort* __restrict__ KT, const ushort* __restrict__ QT, const ushort* __restrict__ V,
    const float* __restrict__ tokens,
    ushort* __restrict__ t2th, ushort* __restrict__ t2tl)
{
    __shared__ ushort Vs[2][64 * 64];   // [dv][k], 8 slots/row, phys = slot ^ (dv&7)
    __shared__ ushort Ks[2][32 * 64];   // [k>>1][k&1 | d], phys = ((k&1)*4 + d/8) ^ (row&7)
    __shared__ ushort Pt[4][64 * 64];   // per-wave [q][k], phys slot = slot ^ (q&7)
    const int tid = threadIdx.x;
    const int wid = tid >> 6, ln = tid & 63, g = ln >> 4, ln15 = ln & 15;
    const int n = blockIdx.z, h = blockIdx.y;
    const int qw = blockIdx.x * 256 + wid * 64;
    const int sw7 = ln15 & 7;

    const ushort* KTh = KT + ((size_t)(n * 16 + h)) * 1024 * 32;
    const ushort* QTh = QT + ((size_t)(n * 16 + h)) * 1024 * 32;
    const ushort* Vh  = V  + ((size_t)(n * 16 + h)) * 64 * 1024;

    short8 qfr[4];
    #pragma unroll
    for (int qf = 0; qf < 4; ++qf)
        qfr[qf] = *(const short8*)&QTh[(qw + qf * 16 + ln15) * 32 + g * 8];

    // staging geometry
    const int vrow = ln >> 3, vcol = (ln & 7) ^ vrow;   // V: pre-swizzled source
    const ushort* vsrc = Vh + (size_t)(wid * 16 + vrow) * 1024 + vcol * 8;
    // K: paired-row layout. lane granule gk = wid*64+ln? No: per-wave 1 issue, 64 granules.
    const int kgr = wid * 64 + ln;          // granule 0..255 over whole 4KB buffer
    const int krow = kgr >> 3, kphys = kgr & 7;
    const int klog = kphys ^ (krow & 7);
    const int kLocal = krow * 2 + (klog >> 2);
    const ushort* ksrc = KTh + (size_t)kLocal * 32 + (klog & 3) * 8;

    gld16(vsrc,            &Vs[0][wid * 1024]);
    gld16(vsrc + 8 * 1024, &Vs[0][wid * 1024 + 512]);
    gld16(ksrc,            &Ks[0][wid * 512]);
    __syncthreads();

    f32x4 acc[4][4];   // [mf][qf]
    #pragma unroll
    for (int mf = 0; mf < 4; ++mf)
        #pragma unroll
        for (int qf = 0; qf < 4; ++qf) acc[mf][qf] = (f32x4){0.f, 0.f, 0.f, 0.f};
    float l_run[4] = {0.f, 0.f, 0.f, 0.f};
    const f32x4 zz = {0.f, 0.f, 0.f, 0.f};
    ushort* pt = &Pt[wid][0];

    for (int kt = 0; kt < 16; ++kt) {
        const int cur = kt & 1;
        if (kt < 15) {
            const int nxt = cur ^ 1;
            const int k0n = (kt + 1) * 64;
            gld16(vsrc + k0n,            &Vs[nxt][wid * 1024]);
            gld16(vsrc + k0n + 8 * 1024, &Vs[nxt][wid * 1024 + 512]);
            gld16(ksrc + k0n * 32,       &Ks[nxt][wid * 512]);
        }
        short8 kf[4];
        #pragma unroll
        for (int mf = 0; mf < 4; ++mf) {
            int k = mf * 16 + ln15;
            int row = k >> 1;
            int logical = (k & 1) * 4 + g * 2;   // d = g*8 -> logical granule (k&1)*4 + g
            // NOTE: granules are 8 ushorts; d=g*8 -> granule index g within 4; need *1:
            int phys = ((k & 1) * 4 + g) ^ (row & 7);
            (void)logical;
            kf[mf] = *(const short8*)&Ks[cur][row * 64 + phys * 8];
        }

        #pragma unroll
        for (int qf = 0; qf < 4; ++qf) {
            f32x4 s[4];
            #pragma unroll
            for (int mf = 0; mf < 4; ++mf)
                s[mf] = __builtin_amdgcn_mfma_f32_16x16x32_bf16(kf[mf], qfr[qf], zz, 0, 0, 0);
            float lacc = 0.f;
            #pragma unroll
            for (int mf = 0; mf < 4; ++mf) {
                float p0 = __builtin_amdgcn_exp2f(s[mf][0]);
                float p1 = __builtin_amdgcn_exp2f(s[mf][1]);
                float p2 = __builtin_amdgcn_exp2f(s[mf][2]);
                float p3 = __builtin_amdgcn_exp2f(s[mf][3]);
                lacc += (p0 + p1) + (p2 + p3);
                union { ushort u[4]; uint2 v; } pk;
                pk.u[0] = f2bfu(p0); pk.u[1] = f2bfu(p1);
                pk.u[2] = f2bfu(p2); pk.u[3] = f2bfu(p3);
                *(uint2*)&pt[(qf * 16 + ln15) * 64 +
                             (((mf * 2 + (g >> 1)) ^ sw7) << 3) + (g & 1) * 4] = pk.v;
            }
            l_run[qf] += lacc;
        }

        #pragma unroll
        for (int ks = 0; ks < 2; ++ks) {
            short8 vf[4];
            #pragma unroll
            for (int mf = 0; mf < 4; ++mf)
                vf[mf] = *(const short8*)&Vs[cur][(mf * 16 + ln15) * 64 +
                                                  (((ks * 4 + g) ^ sw7) << 3)];
            #pragma unroll
            for (int qf = 0; qf < 4; ++qf) {
                short8 pf = *(const short8*)&pt[(qf * 16 + ln15) * 64 +
                                                (((ks * 4 + g) ^ sw7) << 3)];
                #pragma unroll
                for (int mf = 0; mf < 4; ++mf)
                    acc[mf][qf] = __builtin_amdgcn_mfma_f32_16x16x32_bf16(vf[mf], pf, acc[mf][qf], 0, 0, 0);
            }
        }
        __syncthreads();
    }

    #pragma unroll
    for (int qf = 0; qf < 4; ++qf) {
        float l = l_run[qf];
        l += __shfl_xor(l, 16);
        l += __shfl_xor(l, 32);
        float rl = 1.0f / l;
        const int lq = qw + qf * 16 + ln15;
        #pragma unroll
        for (int mf = 0; mf < 4; ++mf) {
            int dv = mf * 16 + g * 4;
            int c = h * 64 + dv;
            size_t base = ((size_t)(n * 1024 + c)) * 1024 + lq;
            union { ushort u[4]; uint2 v; } ph, pl;
            #pragma unroll
            for (int r = 0; r < 4; ++r) {
                float val = acc[mf][qf][r] * rl + tokens[base + (size_t)r * 1024];
                ushort hh = f2bfu(val);
                ph.u[r] = hh;
                pl.u[r] = f2bfu(val - bf2f(hh));
            }
            size_t tb = ((size_t)(n * 1024 + lq)) * 1024 + c;
            *(uint2*)&t2th[tb] = ph.v;
            *(uint2*)&t2tl[tb] = pl.v;
        }
    }
}

// ---------------- conv_f: hi/lo-interleaved swizzled LDS, residual from LDS ----------------
// grid (8 lblk, 8 coblk, NB), block 256 (4 waves 2x2). Tile 128co x 128l, BK=32, 32 kt.
// LDS: AHL 2x16K + XHL 2x16K = 64K -> 2 blocks/CU.
// Row layout (128B): [hi k0..31 | lo k0..31], phys granule = logical ^ (row&7).
__global__ __launch_bounds__(256, 2) void conv_f_mfma(
    const ushort* __restrict__ xh, const ushort* __restrict__ xl,
    const ushort* __restrict__ wh, const ushort* __restrict__ wl,
    const float* __restrict__ bf, float* __restrict__ out)
{
    __shared__ ushort AHL[2][128 * 64];
    __shared__ ushort XHL[2][128 * 64];
    const int l0 = blockIdx.x * 128, co0 = blockIdx.y * 128, n = blockIdx.z;
    const int tid = threadIdx.x;
    const int wid = tid >> 6, ln = tid & 63, g = ln >> 4, ln15 = ln & 15;
    const int wm = wid >> 1, wn = wid & 1;

    // per-lane staging sources (4 issues each for A and X), wave-uniform dests
    const ushort* srcA[4]; const ushort* srcX[4];
    #pragma unroll
    for (int j = 0; j < 4; ++j) {
        int g8 = wid * 64 + ln + j * 256;      // granule 0..1023 (16KB tile)
        int row = g8 >> 3, phys = g8 & 7;
        int logical = phys ^ (row & 7);
        int isLo = logical >> 2, gg = logical & 3;
        srcA[j] = (isLo ? wl : wh) + (size_t)(co0 + row) * 1024 + gg * 8;
        srcX[j] = (isLo ? xl : xh) + ((size_t)(n * 1024 + l0 + row)) * 1024 + gg * 8;
    }

    f32x4 acc[4][4];
    #pragma unroll
    for (int mf = 0; mf < 4; ++mf)
        #pragma unroll
        for (int nf = 0; nf < 4; ++nf) acc[mf][nf] = (f32x4){0.f, 0.f, 0.f, 0.f};

    auto stage = [&](int k0, int b) {
        #pragma unroll
        for (int j = 0; j < 4; ++j) {
            gld16(srcA[j] + k0, &AHL[b][(j * 256 + wid * 64) * 8]);
            gld16(srcX[j] + k0, &XHL[b][(j * 256 + wid * 64) * 8]);
        }
    };

    stage(0, 0);
    __syncthreads();

    const int kt0 = (co0 >> 5) + wm * 2;   // residual-stash kts (wave-uniform)

    for (int kt = 0; kt < 32; ++kt) {
        const int cur = kt & 1;
        if (kt < 31) stage((kt + 1) * 32, cur ^ 1);

        short8 ah[4], al[4], bh[4], bl[4];
        #pragma unroll
        for (int mf = 0; mf < 4; ++mf) {
            const int row = wm * 64 + mf * 16 + ln15;
            ah[mf] = *(const short8*)&AHL[cur][row * 64 + ((g       ^ (row & 7)) << 3)];
            al[mf] = *(const short8*)&AHL[cur][row * 64 + (((4 + g) ^ (row & 7)) << 3)];
        }
        #pragma unroll
        for (int nf = 0; nf < 4; ++nf) {
            const int row = wn * 64 + nf * 16 + ln15;
            bh[nf] = *(const short8*)&XHL[cur][row * 64 + ((g       ^ (row & 7)) << 3)];
            bl[nf] = *(const short8*)&XHL[cur][row * 64 + (((4 + g) ^ (row & 7)) << 3)];
        }
        #pragma unroll
        for (int mf = 0; mf < 4; ++mf)
            #pragma unroll
            for (int nf = 0; nf < 4; ++nf) {
                acc[mf][nf] = __builtin_amdgcn_mfma_f32_16x16x32_bf16(ah[mf], bh[nf], acc[mf][nf], 0, 0, 0);
                acc[mf][nf] = __builtin_amdgcn_mfma_f32_16x16x32_bf16(ah[mf], bl[nf], acc[mf][nf], 0, 0, 0);
                acc[mf][nf] = __builtin_amdgcn_mfma_f32_16x16x32_bf16(al[mf], bh[nf], acc[mf][nf], 0, 0, 0);
            }

        // residual: t2 (= x hi+lo) for co in [kt*32, kt*32+32) lives in XHL[cur]
        if (kt == kt0 || kt == kt0 + 1) {
            const int m0 = (kt == kt0) ? 0 : 2;
            #pragma unroll
            for (int mm = 0; mm < 2; ++mm) {
                const int mf = m0 + mm;
                const int ciG = (mf & 1) * 2 + (g >> 1);   // hi logical granule (ci>>3)
                const int sub = (g & 1) * 4;               // r 0..3 consecutive
                #pragma unroll
                for (int nf = 0; nf < 4; ++nf) {
                    const int row = wn * 64 + nf * 16 + ln15;
                    const ushort* ph_ = &XHL[cur][row * 64 + ((ciG       ^ (row & 7)) << 3) + sub];
                    const ushort* pl_ = &XHL[cur][row * 64 + (((4 + ciG) ^ (row & 7)) << 3) + sub];
                    #pragma unroll
                    for (int r = 0; r < 4; ++r)
                        acc[mf][nf][r] += bf2f(ph_[r]) + bf2f(pl_[r]);
                }
            }
        }
        __syncthreads();
    }

    #pragma unroll
    for (int mf = 0; mf < 4; ++mf) {
        int co = co0 + wm * 64 + mf * 16 + g * 4;
        #pragma unroll
        for (int r = 0; r < 4; ++r) {
            float bb = bf[co + r];
            #pragma unroll
            for (int nf = 0; nf < 4; ++nf) {
                int l = l0 + wn * 64 + nf * 16 + ln15;
                size_t off = ((size_t)(n * 1024 + co + r)) * 1024 + l;
                out[off] = acc[mf][nf][r] + bb;
            }
        }
    }
}

// ---------------- launch ----------------
extern "C" void kernel_launch(void* const* d_in, const int* in_sizes, int n_in,
                              void* d_out, int out_size, void* d_ws, size_t ws_size,
                              hipStream_t stream) {
    const float* tokens = (const float*)d_in[0];
    const float* kw  = (const float*)d_in[1];
    const float* kb_ = (const float*)d_in[2];
    const float* kg  = (const float*)d_in[3];
    const float* kbe = (const float*)d_in[4];
    const float* km  = (const float*)d_in[5];
    const float* kv  = (const float*)d_in[6];
    const float* qw  = (const float*)d_in[7];
    const float* qb_ = (const float*)d_in[8];
    const float* qg  = (const float*)d_in[9];
    const float* qbe = (const float*)d_in[10];
    const float* qm  = (const float*)d_in[11];
    const float* qv  = (const float*)d_in[12];
    const float* vw  = (const float*)d_in[13];
    const float* vb_ = (const float*)d_in[14];
    const float* vg  = (const float*)d_in[15];
    const float* vbe = (const float*)d_in[16];
    const float* vm  = (const float*)d_in[17];
    const float* vv  = (const float*)d_in[18];
    const float* fw  = (const float*)d_in[19];
    const float* fb_ = (const float*)d_in[20];
    const float* fg  = (const float*)d_in[21];
    const float* fbe = (const float*)d_in[22];
    const float* fm  = (const float*)d_in[23];
    const float* fv  = (const float*)d_in[24];

    char* ws = (char*)d_ws;
    ushort* WKQV = (ushort*)(ws + O_WKQV);
    float*  BKQV = (float*)(ws + O_BKQV);
    ushort* WFH  = (ushort*)(ws + O_WFH);
    ushort* WFL  = (ushort*)(ws + O_WFL);
    float*  BF   = (float*)(ws + O_BF);
    ushort* TOKT = (ushort*)(ws + O_TOKT);   // also t2T_hi
    ushort* T2TL = (ushort*)(ws + O_T2TL);
    ushort* KT   = (ushort*)(ws + O_KT);
    ushort* QT   = (ushort*)(ws + O_QT);
    ushort* Vb   = (ushort*)(ws + O_V);
    float*  out  = (float*)d_out;

    prep_all<<<5120, 256, 0, stream>>>(kw, kb_, kg, kbe, km, kv,
                                       qw, qb_, qg, qbe, qm, qv,
                                       vw, vb_, vg, vbe, vm, vv,
                                       fw, fb_, fg, fbe, fm, fv,
                                       WKQV, BKQV, WFH, WFL, BF);
    transpose_tokens<<<dim3(16, 16, NB), 256, 0, stream>>>(tokens, TOKT);
    conv_kqv_mfma<<<dim3(8, 32, NB), 256, 0, stream>>>(TOKT, WKQV, BKQV, KT, QT, Vb);
    attn_mfma<<<dim3(4, 16, NB), 256, 0, stream>>>(KT, QT, Vb, tokens, TOKT, T2TL);
    conv_f_mfma<<<dim3(8, 8, NB), 256, 0, stream>>>(TOKT, T2TL, WFH, WFL, BF, out);
}

// Round 5
// 244.787 us; speedup vs baseline: 2.0436x; 2.0436x over previous
//
#include <hip/hip_runtime.h>
#include <hip/hip_bf16.h>
#include <math.h>

#define NB 8
#define BN_EPS 1e-5f
#define CEXP 0.04508422002778011f  // log2(e)/32

typedef __attribute__((ext_vector_type(4))) float f32x4;
typedef __attribute__((ext_vector_type(8))) short short8;

__device__ __forceinline__ float bf2f(ushort h) {
    union { unsigned u; float f; } v; v.u = ((unsigned)h) << 16;
    return v.f;
}
__device__ __forceinline__ ushort f2bfu(float f) {
    __hip_bfloat16 h = __float2bfloat16(f);
    union { __hip_bfloat16 h; ushort u; } c; c.h = h; return c.u;
}
__device__ __forceinline__ void gld16(const ushort* g, ushort* l) {
    __builtin_amdgcn_global_load_lds(
        (const __attribute__((address_space(1))) void*)g,
        (__attribute__((address_space(3))) void*)l, 16, 0, 0);
}

// ---------------- workspace layout (bytes) ----------------
#define O_WKQV   0u          // ushort[2048*128]
#define O_BKQV   524288u     // float[2048]
#define O_WFH    532480u     // ushort[1024*1024]
#define O_WFL    2629632u    // ushort[1024*1024]
#define O_BF     4726784u    // float[1024]
#define O_TOKT   4730880u    // ushort[8*1024*1024]  (reused as t2T_hi)
#define O_T2TL   21508096u   // ushort[8*1024*1024]
#define O_KT     38285312u   // ushort[8*16*1024*32]
#define O_QT     46673920u   // ushort[8*16*1024*32]
#define O_V      55062528u   // ushort[8*16*64*1024]

// ---------------- prep: fold BN (q also folded with log2e/32), cast to bf16 ----------------
__global__ void prep_all(
    const float* __restrict__ kw, const float* __restrict__ kb, const float* __restrict__ kg,
    const float* __restrict__ kbe, const float* __restrict__ km, const float* __restrict__ kv,
    const float* __restrict__ qw, const float* __restrict__ qb, const float* __restrict__ qg,
    const float* __restrict__ qbe, const float* __restrict__ qm, const float* __restrict__ qv,
    const float* __restrict__ vw, const float* __restrict__ vb, const float* __restrict__ vg,
    const float* __restrict__ vbe, const float* __restrict__ vm, const float* __restrict__ vv,
    const float* __restrict__ fw, const float* __restrict__ fb, const float* __restrict__ fg,
    const float* __restrict__ fbe, const float* __restrict__ fm, const float* __restrict__ fv,
    ushort* __restrict__ wkqv, float* __restrict__ bkqv,
    ushort* __restrict__ wfh, ushort* __restrict__ wfl, float* __restrict__ bff)
{
    int bid = blockIdx.x;
    int tid = threadIdx.x;
    if (bid < 1024) {
        int idx = bid * 256 + tid;       // 0 .. 2048*128-1
        int co = idx >> 7, ci = idx & 127;
        const float *w, *b, *g, *be, *m, *vr; int r; float sc = 1.0f;
        if (co < 512)       { w = kw; b = kb; g = kg; be = kbe; m = km; vr = kv; r = co; }
        else if (co < 1024) { w = qw; b = qb; g = qg; be = qbe; m = qm; vr = qv; r = co - 512; sc = CEXP; }
        else                { w = vw; b = vb; g = vg; be = vbe; m = vm; vr = vv; r = co - 1024; }
        float inv = g[r] * rsqrtf(vr[r] + BN_EPS) * sc;
        wkqv[idx] = f2bfu(w[r * 128 + ci] * inv);
        if (ci == 0) bkqv[co] = (b[r] - m[r]) * inv + be[r] * sc;
    } else {
        int idx = (bid - 1024) * 256 + tid;  // 0 .. 1024*1024-1
        int co = idx >> 10, ci = idx & 1023;
        float inv = fg[co] * rsqrtf(fv[co] + BN_EPS);
        float w = fw[idx] * inv;
        ushort hi = f2bfu(w);
        wfh[idx] = hi;
        wfl[idx] = f2bfu(w - bf2f(hi));
        if (ci == 0) bff[co] = (fb[co] - fm[co]) * inv + fbe[co];
    }
}

// ---------------- transpose tokens: f32 [n][c][l] -> bf16 [n][l][c] ----------------
__global__ __launch_bounds__(256) void transpose_tokens(
    const float* __restrict__ x, ushort* __restrict__ xt)
{
    __shared__ float Ts[64][68];
    const int l0 = blockIdx.x * 64, c0 = blockIdx.y * 64, n = blockIdx.z;
    const int tid = threadIdx.x;
    #pragma unroll
    for (int r = 0; r < 4; ++r) {
        int idx = tid + 256 * r;
        int ci = idx >> 4, li4 = (idx & 15) * 4;
        float4 v4 = *(const float4*)&x[((size_t)(n * 1024 + c0 + ci)) * 1024 + l0 + li4];
        *(float4*)&Ts[ci][li4] = v4;
    }
    __syncthreads();
    #pragma unroll
    for (int r = 0; r < 2; ++r) {
        int idx = tid + 256 * r;
        int lr = idx >> 3, oc = idx & 7;
        union { ushort u[8]; uint4 v; } pk;
        #pragma unroll
        for (int i = 0; i < 8; ++i) pk.u[i] = f2bfu(Ts[oc * 8 + i][lr]);
        *(uint4*)&xt[((size_t)(n * 1024 + l0 + lr)) * 1024 + c0 + oc * 8] = pk.v;
    }
}

// ---------------- conv_kqv: bf16 MFMA GEMM, gld16 staging, writes KT/QT + V ----------------
// grid (8 lblk, 32 coblk, NB), block 256 (4 waves 2x2). Tile 64co x 128l, K=128.
__global__ __launch_bounds__(256) void conv_kqv_mfma(
    const ushort* __restrict__ xt, const ushort* __restrict__ wq,
    const float* __restrict__ bq,
    ushort* __restrict__ KT, ushort* __restrict__ QT, ushort* __restrict__ V)
{
    __shared__ ushort Ws[64 * 128];   // [co][ci], 16 slots/row, phys slot = logical ^ (row&15)
    __shared__ ushort Xs[128 * 128];  // [l][ci]
    const int l0 = blockIdx.x * 128, co0 = blockIdx.y * 64, n = blockIdx.z;
    const int tid = threadIdx.x;
    const int wid = tid >> 6, ln = tid & 63, g = ln >> 4, ln15 = ln & 15;
    const int wm = wid >> 1, wn = wid & 1;

    int in_off;
    if (co0 < 512)       in_off = (co0 >> 6) << 7;
    else if (co0 < 1024) in_off = ((co0 - 512) >> 6) << 7;
    else                 in_off = ((co0 - 1024) >> 7) << 7;

    // W: 64 rows x 256B = 1024 granules -> 4 issues
    #pragma unroll
    for (int j = 0; j < 4; ++j) {
        int g16 = wid * 64 + ln + j * 256;
        int row = g16 >> 4, phys = g16 & 15;
        int logical = phys ^ (row & 15);
        gld16(wq + (size_t)(co0 + row) * 128 + logical * 8,
              &Ws[(j * 256 + wid * 64) * 8]);
    }
    // X: 128 rows x 256B = 2048 granules -> 8 issues
    #pragma unroll
    for (int j = 0; j < 8; ++j) {
        int g16 = wid * 64 + ln + j * 256;
        int row = g16 >> 4, phys = g16 & 15;
        int logical = phys ^ (row & 15);
        gld16(xt + ((size_t)(n * 1024 + l0 + row)) * 1024 + in_off + logical * 8,
              &Xs[(j * 256 + wid * 64) * 8]);
    }
    __syncthreads();

    f32x4 acc[2][4];
    #pragma unroll
    for (int mf = 0; mf < 2; ++mf)
        #pragma unroll
        for (int nf = 0; nf < 4; ++nf) acc[mf][nf] = (f32x4){0.f, 0.f, 0.f, 0.f};

    #pragma unroll
    for (int ks = 0; ks < 4; ++ks) {
        short8 a[2], b[4];
        #pragma unroll
        for (int mf = 0; mf < 2; ++mf) {
            int row = wm * 32 + mf * 16 + ln15;
            int slot = ks * 4 + g;
            a[mf] = *(const short8*)&Ws[row * 128 + ((slot ^ (row & 15)) << 3)];
        }
        #pragma unroll
        for (int nf = 0; nf < 4; ++nf) {
            int row = wn * 64 + nf * 16 + ln15;
            int slot = ks * 4 + g;
            b[nf] = *(const short8*)&Xs[row * 128 + ((slot ^ (row & 15)) << 3)];
        }
        #pragma unroll
        for (int mf = 0; mf < 2; ++mf)
            #pragma unroll
            for (int nf = 0; nf < 4; ++nf)
                acc[mf][nf] = __builtin_amdgcn_mfma_f32_16x16x32_bf16(a[mf], b[nf], acc[mf][nf], 0, 0, 0);
    }

    #pragma unroll
    for (int mf = 0; mf < 2; ++mf) {
        int m0 = wm * 32 + mf * 16 + g * 4;
        int co = co0 + m0;
        float bb[4];
        #pragma unroll
        for (int r = 0; r < 4; ++r) bb[r] = bq[co + r];
        #pragma unroll
        for (int nf = 0; nf < 4; ++nf) {
            int l = l0 + wn * 64 + nf * 16 + ln15;
            float v0 = acc[mf][nf][0] + bb[0];
            float v1 = acc[mf][nf][1] + bb[1];
            float v2 = acc[mf][nf][2] + bb[2];
            float v3 = acc[mf][nf][3] + bb[3];
            if (co0 < 512) {
                int h = co >> 5, d = m0 & 31;
                union { ushort u[4]; uint2 v; } pk;
                pk.u[0] = f2bfu(v0); pk.u[1] = f2bfu(v1); pk.u[2] = f2bfu(v2); pk.u[3] = f2bfu(v3);
                *(uint2*)&KT[(((size_t)(n * 16 + h)) * 1024 + l) * 32 + d] = pk.v;
            } else if (co0 < 1024) {
                int cq = co - 512; int h = cq >> 5, d = m0 & 31;
                union { ushort u[4]; uint2 v; } pk;
                pk.u[0] = f2bfu(v0); pk.u[1] = f2bfu(v1); pk.u[2] = f2bfu(v2); pk.u[3] = f2bfu(v3);
                *(uint2*)&QT[(((size_t)(n * 16 + h)) * 1024 + l) * 32 + d] = pk.v;
            } else {
                int cv = co - 1024; int h = cv >> 6, dv = cv & 63;
                size_t base = (((size_t)(n * 16 + h)) * 64 + dv) * 1024 + l;
                V[base]          = f2bfu(v0);
                V[base + 1024]   = f2bfu(v1);
                V[base + 2048]   = f2bfu(v2);
                V[base + 3072]   = f2bfu(v3);
            }
        }
    }
}

// ---------------- attention: 64 q/wave, LDS K/V dbuf, no-max softmax, MFMA ----------------
// grid (4 qblk, 16 h, NB), block 256 (4 waves). Wave owns 64 q; block 256 q.
// LDS: Vs 16K + Ks 8K + Pt 32K = 56K -> 2 blocks/CU.
__global__ __launch_bounds__(256, 2) void attn_mfma(
    const ushort* __restrict__ KT, const ushort* __restrict__ QT, const ushort* __restrict__ V,
    const float* __restrict__ tokens,
    ushort* __restrict__ t2th, ushort* __restrict__ t2tl)
{
    __shared__ ushort Vs[2][64 * 64];   // [dv][k], 8 slots/row, phys = slot ^ (dv&7)
    __shared__ ushort Ks[2][32 * 64];   // paired-row: [k>>1][(k&1)*4+g granules], phys ^ (row&7)
    __shared__ ushort Pt[4][64 * 64];   // per-wave [q][k], phys slot = slot ^ (q&7)
    const int tid = threadIdx.x;
    const int wid = tid >> 6, ln = tid & 63, g = ln >> 4, ln15 = ln & 15;
    const int n = blockIdx.z, h = blockIdx.y;
    const int qw = blockIdx.x * 256 + wid * 64;
    const int sw7 = ln15 & 7;

    const ushort* KTh = KT + ((size_t)(n * 16 + h)) * 1024 * 32;
    const ushort* QTh = QT + ((size_t)(n * 16 + h)) * 1024 * 32;
    const ushort* Vh  = V  + ((size_t)(n * 16 + h)) * 64 * 1024;

    short8 qfr[4];
    #pragma unroll
    for (int qf = 0; qf < 4; ++qf)
        qfr[qf] = *(const short8*)&QTh[(qw + qf * 16 + ln15) * 32 + g * 8];

    // staging geometry
    const int vrow = ln >> 3, vcol = (ln & 7) ^ vrow;   // V: pre-swizzled source
    const ushort* vsrc = Vh + (size_t)(wid * 16 + vrow) * 1024 + vcol * 8;
    const int kgr = wid * 64 + ln;          // granule 0..255 over whole 4KB buffer
    const int krow = kgr >> 3, kphys = kgr & 7;
    const int klog = kphys ^ (krow & 7);
    const int kLocal = krow * 2 + (klog >> 2);
    const ushort* ksrc = KTh + (size_t)kLocal * 32 + (klog & 3) * 8;

    gld16(vsrc,            &Vs[0][wid * 1024]);
    gld16(vsrc + 8 * 1024, &Vs[0][wid * 1024 + 512]);
    gld16(ksrc,            &Ks[0][wid * 512]);
    __syncthreads();

    f32x4 acc[4][4];   // [mf][qf]
    #pragma unroll
    for (int mf = 0; mf < 4; ++mf)
        #pragma unroll
        for (int qf = 0; qf < 4; ++qf) acc[mf][qf] = (f32x4){0.f, 0.f, 0.f, 0.f};
    float l_run[4] = {0.f, 0.f, 0.f, 0.f};
    const f32x4 zz = {0.f, 0.f, 0.f, 0.f};
    ushort* pt = &Pt[wid][0];

    for (int kt = 0; kt < 16; ++kt) {
        const int cur = kt & 1;
        if (kt < 15) {
            const int nxt = cur ^ 1;
            const int k0n = (kt + 1) * 64;
            gld16(vsrc + k0n,            &Vs[nxt][wid * 1024]);
            gld16(vsrc + k0n + 8 * 1024, &Vs[nxt][wid * 1024 + 512]);
            gld16(ksrc + k0n * 32,       &Ks[nxt][wid * 512]);
        }
        short8 kf[4];
        #pragma unroll
        for (int mf = 0; mf < 4; ++mf) {
            int k = mf * 16 + ln15;
            int row = k >> 1;
            int phys = ((k & 1) * 4 + g) ^ (row & 7);
            kf[mf] = *(const short8*)&Ks[cur][row * 64 + phys * 8];
        }

        #pragma unroll
        for (int qf = 0; qf < 4; ++qf) {
            f32x4 s[4];
            #pragma unroll
            for (int mf = 0; mf < 4; ++mf)
                s[mf] = __builtin_amdgcn_mfma_f32_16x16x32_bf16(kf[mf], qfr[qf], zz, 0, 0, 0);
            float lacc = 0.f;
            #pragma unroll
            for (int mf = 0; mf < 4; ++mf) {
                float p0 = __builtin_amdgcn_exp2f(s[mf][0]);
                float p1 = __builtin_amdgcn_exp2f(s[mf][1]);
                float p2 = __builtin_amdgcn_exp2f(s[mf][2]);
                float p3 = __builtin_amdgcn_exp2f(s[mf][3]);
                lacc += (p0 + p1) + (p2 + p3);
                union { ushort u[4]; uint2 v; } pk;
                pk.u[0] = f2bfu(p0); pk.u[1] = f2bfu(p1);
                pk.u[2] = f2bfu(p2); pk.u[3] = f2bfu(p3);
                *(uint2*)&pt[(qf * 16 + ln15) * 64 +
                             (((mf * 2 + (g >> 1)) ^ sw7) << 3) + (g & 1) * 4] = pk.v;
            }
            l_run[qf] += lacc;
        }

        #pragma unroll
        for (int ks = 0; ks < 2; ++ks) {
            short8 vf[4];
            #pragma unroll
            for (int mf = 0; mf < 4; ++mf)
                vf[mf] = *(const short8*)&Vs[cur][(mf * 16 + ln15) * 64 +
                                                  (((ks * 4 + g) ^ sw7) << 3)];
            #pragma unroll
            for (int qf = 0; qf < 4; ++qf) {
                short8 pf = *(const short8*)&pt[(qf * 16 + ln15) * 64 +
                                                (((ks * 4 + g) ^ sw7) << 3)];
                #pragma unroll
                for (int mf = 0; mf < 4; ++mf)
                    acc[mf][qf] = __builtin_amdgcn_mfma_f32_16x16x32_bf16(vf[mf], pf, acc[mf][qf], 0, 0, 0);
            }
        }
        __syncthreads();
    }

    #pragma unroll
    for (int qf = 0; qf < 4; ++qf) {
        float l = l_run[qf];
        l += __shfl_xor(l, 16);
        l += __shfl_xor(l, 32);
        float rl = 1.0f / l;
        const int lq = qw + qf * 16 + ln15;
        #pragma unroll
        for (int mf = 0; mf < 4; ++mf) {
            int dv = mf * 16 + g * 4;
            int c = h * 64 + dv;
            size_t base = ((size_t)(n * 1024 + c)) * 1024 + lq;
            union { ushort u[4]; uint2 v; } ph, pl;
            #pragma unroll
            for (int r = 0; r < 4; ++r) {
                float val = acc[mf][qf][r] * rl + tokens[base + (size_t)r * 1024];
                ushort hh = f2bfu(val);
                ph.u[r] = hh;
                pl.u[r] = f2bfu(val - bf2f(hh));
            }
            size_t tb = ((size_t)(n * 1024 + lq)) * 1024 + c;
            *(uint2*)&t2th[tb] = ph.v;
            *(uint2*)&t2tl[tb] = pl.v;
        }
    }
}

// ---------------- conv_f: hi/lo-interleaved swizzled LDS, residual from LDS ----------------
// grid (8 lblk, 8 coblk, NB), block 256 (4 waves 2x2). Tile 128co x 128l, BK=32, 32 kt.
// LDS: AHL 2x16K + XHL 2x16K = 64K -> 2 blocks/CU.
// Row layout (128B): [hi k0..31 | lo k0..31], phys granule = logical ^ (row&7).
// NOTE: residual-add branches use LITERAL acc indices only (rule #20: runtime
// index -> acc demoted to scratch; that was round 4's 1 GB WRITE_SIZE bug).
__global__ __launch_bounds__(256, 2) void conv_f_mfma(
    const ushort* __restrict__ xh, const ushort* __restrict__ xl,
    const ushort* __restrict__ wh, const ushort* __restrict__ wl,
    const float* __restrict__ bf, float* __restrict__ out)
{
    __shared__ ushort AHL[2][128 * 64];
    __shared__ ushort XHL[2][128 * 64];
    const int l0 = blockIdx.x * 128, co0 = blockIdx.y * 128, n = blockIdx.z;
    const int tid = threadIdx.x;
    const int wid = tid >> 6, ln = tid & 63, g = ln >> 4, ln15 = ln & 15;
    const int wm = wid >> 1, wn = wid & 1;

    // per-lane staging sources (4 issues each for A and X), wave-uniform dests
    const ushort* srcA[4]; const ushort* srcX[4];
    #pragma unroll
    for (int j = 0; j < 4; ++j) {
        int g8 = wid * 64 + ln + j * 256;      // granule 0..1023 (16KB tile)
        int row = g8 >> 3, phys = g8 & 7;
        int logical = phys ^ (row & 7);
        int isLo = logical >> 2, gg = logical & 3;
        srcA[j] = (isLo ? wl : wh) + (size_t)(co0 + row) * 1024 + gg * 8;
        srcX[j] = (isLo ? xl : xh) + ((size_t)(n * 1024 + l0 + row)) * 1024 + gg * 8;
    }

    f32x4 acc[4][4];
    #pragma unroll
    for (int mf = 0; mf < 4; ++mf)
        #pragma unroll
        for (int nf = 0; nf < 4; ++nf) acc[mf][nf] = (f32x4){0.f, 0.f, 0.f, 0.f};

    auto stage = [&](int k0, int b) {
        #pragma unroll
        for (int j = 0; j < 4; ++j) {
            gld16(srcA[j] + k0, &AHL[b][(j * 256 + wid * 64) * 8]);
            gld16(srcX[j] + k0, &XHL[b][(j * 256 + wid * 64) * 8]);
        }
    };

    stage(0, 0);
    __syncthreads();

    const int kt0 = (co0 >> 5) + wm * 2;   // residual-stash kts (wave-uniform)
    const int sub = (g & 1) * 4;
    const int ciG0 = (g >> 1);             // granule for mf even
    const int ciG1 = 2 + (g >> 1);         // granule for mf odd

    for (int kt = 0; kt < 32; ++kt) {
        const int cur = kt & 1;
        if (kt < 31) stage((kt + 1) * 32, cur ^ 1);

        short8 ah[4], al[4], bh[4], bl[4];
        #pragma unroll
        for (int mf = 0; mf < 4; ++mf) {
            const int row = wm * 64 + mf * 16 + ln15;
            ah[mf] = *(const short8*)&AHL[cur][row * 64 + ((g       ^ (row & 7)) << 3)];
            al[mf] = *(const short8*)&AHL[cur][row * 64 + (((4 + g) ^ (row & 7)) << 3)];
        }
        #pragma unroll
        for (int nf = 0; nf < 4; ++nf) {
            const int row = wn * 64 + nf * 16 + ln15;
            bh[nf] = *(const short8*)&XHL[cur][row * 64 + ((g       ^ (row & 7)) << 3)];
            bl[nf] = *(const short8*)&XHL[cur][row * 64 + (((4 + g) ^ (row & 7)) << 3)];
        }
        #pragma unroll
        for (int mf = 0; mf < 4; ++mf)
            #pragma unroll
            for (int nf = 0; nf < 4; ++nf) {
                acc[mf][nf] = __builtin_amdgcn_mfma_f32_16x16x32_bf16(ah[mf], bh[nf], acc[mf][nf], 0, 0, 0);
                acc[mf][nf] = __builtin_amdgcn_mfma_f32_16x16x32_bf16(ah[mf], bl[nf], acc[mf][nf], 0, 0, 0);
                acc[mf][nf] = __builtin_amdgcn_mfma_f32_16x16x32_bf16(al[mf], bh[nf], acc[mf][nf], 0, 0, 0);
            }

        // residual: t2 (= x hi+lo) for co in [kt*32, kt*32+32) lives in XHL[cur].
        // All acc indices are LITERALS (two static branches) to stay in registers.
        if (kt == kt0) {
            #pragma unroll
            for (int nf = 0; nf < 4; ++nf) {
                const int row = wn * 64 + nf * 16 + ln15;
                const ushort* p0h = &XHL[cur][row * 64 + ((ciG0       ^ (row & 7)) << 3) + sub];
                const ushort* p0l = &XHL[cur][row * 64 + (((4 + ciG0) ^ (row & 7)) << 3) + sub];
                const ushort* p1h = &XHL[cur][row * 64 + ((ciG1       ^ (row & 7)) << 3) + sub];
                const ushort* p1l = &XHL[cur][row * 64 + (((4 + ciG1) ^ (row & 7)) << 3) + sub];
                #pragma unroll
                for (int r = 0; r < 4; ++r) {
                    acc[0][nf][r] += bf2f(p0h[r]) + bf2f(p0l[r]);
                    acc[1][nf][r] += bf2f(p1h[r]) + bf2f(p1l[r]);
                }
            }
        } else if (kt == kt0 + 1) {
            #pragma unroll
            for (int nf = 0; nf < 4; ++nf) {
                const int row = wn * 64 + nf * 16 + ln15;
                const ushort* p0h = &XHL[cur][row * 64 + ((ciG0       ^ (row & 7)) << 3) + sub];
                const ushort* p0l = &XHL[cur][row * 64 + (((4 + ciG0) ^ (row & 7)) << 3) + sub];
                const ushort* p1h = &XHL[cur][row * 64 + ((ciG1       ^ (row & 7)) << 3) + sub];
                const ushort* p1l = &XHL[cur][row * 64 + (((4 + ciG1) ^ (row & 7)) << 3) + sub];
                #pragma unroll
                for (int r = 0; r < 4; ++r) {
                    acc[2][nf][r] += bf2f(p0h[r]) + bf2f(p0l[r]);
                    acc[3][nf][r] += bf2f(p1h[r]) + bf2f(p1l[r]);
                }
            }
        }
        __syncthreads();
    }

    #pragma unroll
    for (int mf = 0; mf < 4; ++mf) {
        int co = co0 + wm * 64 + mf * 16 + g * 4;
        #pragma unroll
        for (int r = 0; r < 4; ++r) {
            float bb = bf[co + r];
            #pragma unroll
            for (int nf = 0; nf < 4; ++nf) {
                int l = l0 + wn * 64 + nf * 16 + ln15;
                size_t off = ((size_t)(n * 1024 + co + r)) * 1024 + l;
                out[off] = acc[mf][nf][r] + bb;
            }
        }
    }
}

// ---------------- launch ----------------
extern "C" void kernel_launch(void* const* d_in, const int* in_sizes, int n_in,
                              void* d_out, int out_size, void* d_ws, size_t ws_size,
                              hipStream_t stream) {
    const float* tokens = (const float*)d_in[0];
    const float* kw  = (const float*)d_in[1];
    const float* kb_ = (const float*)d_in[2];
    const float* kg  = (const float*)d_in[3];
    const float* kbe = (const float*)d_in[4];
    const float* km  = (const float*)d_in[5];
    const float* kv  = (const float*)d_in[6];
    const float* qw  = (const float*)d_in[7];
    const float* qb_ = (const float*)d_in[8];
    const float* qg  = (const float*)d_in[9];
    const float* qbe = (const float*)d_in[10];
    const float* qm  = (const float*)d_in[11];
    const float* qv  = (const float*)d_in[12];
    const float* vw  = (const float*)d_in[13];
    const float* vb_ = (const float*)d_in[14];
    const float* vg  = (const float*)d_in[15];
    const float* vbe = (const float*)d_in[16];
    const float* vm  = (const float*)d_in[17];
    const float* vv  = (const float*)d_in[18];
    const float* fw  = (const float*)d_in[19];
    const float* fb_ = (const float*)d_in[20];
    const float* fg  = (const float*)d_in[21];
    const float* fbe = (const float*)d_in[22];
    const float* fm  = (const float*)d_in[23];
    const float* fv  = (const float*)d_in[24];

    char* ws = (char*)d_ws;
    ushort* WKQV = (ushort*)(ws + O_WKQV);
    float*  BKQV = (float*)(ws + O_BKQV);
    ushort* WFH  = (ushort*)(ws + O_WFH);
    ushort* WFL  = (ushort*)(ws + O_WFL);
    float*  BF   = (float*)(ws + O_BF);
    ushort* TOKT = (ushort*)(ws + O_TOKT);   // also t2T_hi
    ushort* T2TL = (ushort*)(ws + O_T2TL);
    ushort* KT   = (ushort*)(ws + O_KT);
    ushort* QT   = (ushort*)(ws + O_QT);
    ushort* Vb   = (ushort*)(ws + O_V);
    float*  out  = (float*)d_out;

    prep_all<<<5120, 256, 0, stream>>>(kw, kb_, kg, kbe, km, kv,
                                       qw, qb_, qg, qbe, qm, qv,
                                       vw, vb_, vg, vbe, vm, vv,
                                       fw, fb_, fg, fbe, fm, fv,
                                       WKQV, BKQV, WFH, WFL, BF);
    transpose_tokens<<<dim3(16, 16, NB), 256, 0, stream>>>(tokens, TOKT);
    conv_kqv_mfma<<<dim3(8, 32, NB), 256, 0, stream>>>(TOKT, WKQV, BKQV, KT, QT, Vb);
    attn_mfma<<<dim3(4, 16, NB), 256, 0, stream>>>(KT, QT, Vb, tokens, TOKT, T2TL);
    conv_f_mfma<<<dim3(8, 8, NB), 256, 0, stream>>>(TOKT, T2TL, WFH, WFL, BF, out);
}

// Round 6
// 218.624 us; speedup vs baseline: 2.2882x; 1.1197x over previous
//
#include <hip/hip_runtime.h>
#include <hip/hip_bf16.h>
#include <math.h>

#define NB 8
#define BN_EPS 1e-5f
#define CEXP 0.04508422002778011f  // log2(e)/32

typedef __attribute__((ext_vector_type(4))) float f32x4;
typedef __attribute__((ext_vector_type(8))) short short8;

__device__ __forceinline__ float bf2f(ushort h) {
    union { unsigned u; float f; } v; v.u = ((unsigned)h) << 16;
    return v.f;
}
__device__ __forceinline__ ushort f2bfu(float f) {
    __hip_bfloat16 h = __float2bfloat16(f);
    union { __hip_bfloat16 h; ushort u; } c; c.h = h; return c.u;
}
__device__ __forceinline__ void gld16(const ushort* g, ushort* l) {
    __builtin_amdgcn_global_load_lds(
        (const __attribute__((address_space(1))) void*)g,
        (__attribute__((address_space(3))) void*)l, 16, 0, 0);
}

// ---------------- workspace layout (bytes) ----------------
#define O_WKQV   0u          // ushort[2048*128]
#define O_BKQV   524288u     // float[2048]
#define O_WFH    532480u     // ushort[1024*1024]
#define O_WFL    2629632u    // (unused this round)
#define O_BF     4726784u    // float[1024]
#define O_TOKT   4730880u    // ushort[8*1024*1024]  (tokensT, reused as t2T_hi [n][l][c])
#define O_T2LO   21508096u   // ushort[8*1024*1024]  t2 lo-correction, [n][c][l]
#define O_KT     38285312u   // ushort[8*16*1024*32]
#define O_QT     46673920u   // ushort[8*16*1024*32]
#define O_V      55062528u   // ushort[8*16*64*1024]

// ---------------- prep: fold BN (q also folded with log2e/32), cast to bf16 ----------------
__global__ void prep_all(
    const float* __restrict__ kw, const float* __restrict__ kb, const float* __restrict__ kg,
    const float* __restrict__ kbe, const float* __restrict__ km, const float* __restrict__ kv,
    const float* __restrict__ qw, const float* __restrict__ qb, const float* __restrict__ qg,
    const float* __restrict__ qbe, const float* __restrict__ qm, const float* __restrict__ qv,
    const float* __restrict__ vw, const float* __restrict__ vb, const float* __restrict__ vg,
    const float* __restrict__ vbe, const float* __restrict__ vm, const float* __restrict__ vv,
    const float* __restrict__ fw, const float* __restrict__ fb, const float* __restrict__ fg,
    const float* __restrict__ fbe, const float* __restrict__ fm, const float* __restrict__ fv,
    ushort* __restrict__ wkqv, float* __restrict__ bkqv,
    ushort* __restrict__ wfh, float* __restrict__ bff)
{
    int bid = blockIdx.x;
    int tid = threadIdx.x;
    if (bid < 1024) {
        int idx = bid * 256 + tid;       // 0 .. 2048*128-1
        int co = idx >> 7, ci = idx & 127;
        const float *w, *b, *g, *be, *m, *vr; int r; float sc = 1.0f;
        if (co < 512)       { w = kw; b = kb; g = kg; be = kbe; m = km; vr = kv; r = co; }
        else if (co < 1024) { w = qw; b = qb; g = qg; be = qbe; m = qm; vr = qv; r = co - 512; sc = CEXP; }
        else                { w = vw; b = vb; g = vg; be = vbe; m = vm; vr = vv; r = co - 1024; }
        float inv = g[r] * rsqrtf(vr[r] + BN_EPS) * sc;
        wkqv[idx] = f2bfu(w[r * 128 + ci] * inv);
        if (ci == 0) bkqv[co] = (b[r] - m[r]) * inv + be[r] * sc;
    } else {
        int idx = (bid - 1024) * 256 + tid;  // 0 .. 1024*1024-1
        int co = idx >> 10, ci = idx & 1023;
        float inv = fg[co] * rsqrtf(fv[co] + BN_EPS);
        wfh[idx] = f2bfu(fw[idx] * inv);
        if (ci == 0) bff[co] = (fb[co] - fm[co]) * inv + fbe[co];
    }
}

// ---------------- transpose tokens: f32 [n][c][l] -> bf16 [n][l][c] ----------------
__global__ __launch_bounds__(256) void transpose_tokens(
    const float* __restrict__ x, ushort* __restrict__ xt)
{
    __shared__ float Ts[64][68];
    const int l0 = blockIdx.x * 64, c0 = blockIdx.y * 64, n = blockIdx.z;
    const int tid = threadIdx.x;
    #pragma unroll
    for (int r = 0; r < 4; ++r) {
        int idx = tid + 256 * r;
        int ci = idx >> 4, li4 = (idx & 15) * 4;
        float4 v4 = *(const float4*)&x[((size_t)(n * 1024 + c0 + ci)) * 1024 + l0 + li4];
        *(float4*)&Ts[ci][li4] = v4;
    }
    __syncthreads();
    #pragma unroll
    for (int r = 0; r < 2; ++r) {
        int idx = tid + 256 * r;
        int lr = idx >> 3, oc = idx & 7;
        union { ushort u[8]; uint4 v; } pk;
        #pragma unroll
        for (int i = 0; i < 8; ++i) pk.u[i] = f2bfu(Ts[oc * 8 + i][lr]);
        *(uint4*)&xt[((size_t)(n * 1024 + l0 + lr)) * 1024 + c0 + oc * 8] = pk.v;
    }
}

// ---------------- conv_kqv: bf16 MFMA GEMM, gld16 staging, writes KT/QT + V ----------------
// grid (8 lblk, 32 coblk, NB), block 256 (4 waves 2x2). Tile 64co x 128l, K=128.
__global__ __launch_bounds__(256) void conv_kqv_mfma(
    const ushort* __restrict__ xt, const ushort* __restrict__ wq,
    const float* __restrict__ bq,
    ushort* __restrict__ KT, ushort* __restrict__ QT, ushort* __restrict__ V)
{
    __shared__ ushort Ws[64 * 128];   // [co][ci], 16 slots/row, phys slot = logical ^ (row&15)
    __shared__ ushort Xs[128 * 128];  // [l][ci]
    const int l0 = blockIdx.x * 128, co0 = blockIdx.y * 64, n = blockIdx.z;
    const int tid = threadIdx.x;
    const int wid = tid >> 6, ln = tid & 63, g = ln >> 4, ln15 = ln & 15;
    const int wm = wid >> 1, wn = wid & 1;

    int in_off;
    if (co0 < 512)       in_off = (co0 >> 6) << 7;
    else if (co0 < 1024) in_off = ((co0 - 512) >> 6) << 7;
    else                 in_off = ((co0 - 1024) >> 7) << 7;

    // W: 64 rows x 256B = 1024 granules -> 4 issues
    #pragma unroll
    for (int j = 0; j < 4; ++j) {
        int g16 = wid * 64 + ln + j * 256;
        int row = g16 >> 4, phys = g16 & 15;
        int logical = phys ^ (row & 15);
        gld16(wq + (size_t)(co0 + row) * 128 + logical * 8,
              &Ws[(j * 256 + wid * 64) * 8]);
    }
    // X: 128 rows x 256B = 2048 granules -> 8 issues
    #pragma unroll
    for (int j = 0; j < 8; ++j) {
        int g16 = wid * 64 + ln + j * 256;
        int row = g16 >> 4, phys = g16 & 15;
        int logical = phys ^ (row & 15);
        gld16(xt + ((size_t)(n * 1024 + l0 + row)) * 1024 + in_off + logical * 8,
              &Xs[(j * 256 + wid * 64) * 8]);
    }
    __syncthreads();

    f32x4 acc[2][4];
    #pragma unroll
    for (int mf = 0; mf < 2; ++mf)
        #pragma unroll
        for (int nf = 0; nf < 4; ++nf) acc[mf][nf] = (f32x4){0.f, 0.f, 0.f, 0.f};

    #pragma unroll
    for (int ks = 0; ks < 4; ++ks) {
        short8 a[2], b[4];
        #pragma unroll
        for (int mf = 0; mf < 2; ++mf) {
            int row = wm * 32 + mf * 16 + ln15;
            int slot = ks * 4 + g;
            a[mf] = *(const short8*)&Ws[row * 128 + ((slot ^ (row & 15)) << 3)];
        }
        #pragma unroll
        for (int nf = 0; nf < 4; ++nf) {
            int row = wn * 64 + nf * 16 + ln15;
            int slot = ks * 4 + g;
            b[nf] = *(const short8*)&Xs[row * 128 + ((slot ^ (row & 15)) << 3)];
        }
        #pragma unroll
        for (int mf = 0; mf < 2; ++mf)
            #pragma unroll
            for (int nf = 0; nf < 4; ++nf)
                acc[mf][nf] = __builtin_amdgcn_mfma_f32_16x16x32_bf16(a[mf], b[nf], acc[mf][nf], 0, 0, 0);
    }

    #pragma unroll
    for (int mf = 0; mf < 2; ++mf) {
        int m0 = wm * 32 + mf * 16 + g * 4;
        int co = co0 + m0;
        float bb[4];
        #pragma unroll
        for (int r = 0; r < 4; ++r) bb[r] = bq[co + r];
        #pragma unroll
        for (int nf = 0; nf < 4; ++nf) {
            int l = l0 + wn * 64 + nf * 16 + ln15;
            float v0 = acc[mf][nf][0] + bb[0];
            float v1 = acc[mf][nf][1] + bb[1];
            float v2 = acc[mf][nf][2] + bb[2];
            float v3 = acc[mf][nf][3] + bb[3];
            if (co0 < 512) {
                int h = co >> 5, d = m0 & 31;
                union { ushort u[4]; uint2 v; } pk;
                pk.u[0] = f2bfu(v0); pk.u[1] = f2bfu(v1); pk.u[2] = f2bfu(v2); pk.u[3] = f2bfu(v3);
                *(uint2*)&KT[(((size_t)(n * 16 + h)) * 1024 + l) * 32 + d] = pk.v;
            } else if (co0 < 1024) {
                int cq = co - 512; int h = cq >> 5, d = m0 & 31;
                union { ushort u[4]; uint2 v; } pk;
                pk.u[0] = f2bfu(v0); pk.u[1] = f2bfu(v1); pk.u[2] = f2bfu(v2); pk.u[3] = f2bfu(v3);
                *(uint2*)&QT[(((size_t)(n * 16 + h)) * 1024 + l) * 32 + d] = pk.v;
            } else {
                int cv = co - 1024; int h = cv >> 6, dv = cv & 63;
                size_t base = (((size_t)(n * 16 + h)) * 64 + dv) * 1024 + l;
                V[base]          = f2bfu(v0);
                V[base + 1024]   = f2bfu(v1);
                V[base + 2048]   = f2bfu(v2);
                V[base + 3072]   = f2bfu(v3);
            }
        }
    }
}

// ---------------- attention: 64 q/wave, LDS K/V dbuf, no-max softmax, MFMA ----------------
// grid (4 qblk, 16 h, NB), block 256 (4 waves). Wave owns 64 q; block 256 q.
// LDS: Vs 16K + Ks 8K + Pt 32K = 56K -> 2 blocks/CU.
__global__ __launch_bounds__(256, 2) void attn_mfma(
    const ushort* __restrict__ KT, const ushort* __restrict__ QT, const ushort* __restrict__ V,
    const float* __restrict__ tokens,
    ushort* __restrict__ t2th, ushort* __restrict__ t2lo)
{
    __shared__ ushort Vs[2][64 * 64];   // [dv][k], 8 slots/row, phys = slot ^ (dv&7)
    __shared__ ushort Ks[2][32 * 64];   // paired-row: [k>>1][(k&1)*4+g granules], phys ^ (row&7)
    __shared__ ushort Pt[4][64 * 64];   // per-wave [q][k], phys slot = slot ^ (q&7)
    const int tid = threadIdx.x;
    const int wid = tid >> 6, ln = tid & 63, g = ln >> 4, ln15 = ln & 15;
    const int n = blockIdx.z, h = blockIdx.y;
    const int qw = blockIdx.x * 256 + wid * 64;
    const int sw7 = ln15 & 7;

    const ushort* KTh = KT + ((size_t)(n * 16 + h)) * 1024 * 32;
    const ushort* QTh = QT + ((size_t)(n * 16 + h)) * 1024 * 32;
    const ushort* Vh  = V  + ((size_t)(n * 16 + h)) * 64 * 1024;

    short8 qfr[4];
    #pragma unroll
    for (int qf = 0; qf < 4; ++qf)
        qfr[qf] = *(const short8*)&QTh[(qw + qf * 16 + ln15) * 32 + g * 8];

    // staging geometry
    const int vrow = ln >> 3, vcol = (ln & 7) ^ vrow;   // V: pre-swizzled source
    const ushort* vsrc = Vh + (size_t)(wid * 16 + vrow) * 1024 + vcol * 8;
    const int kgr = wid * 64 + ln;          // granule 0..255 over whole 4KB buffer
    const int krow = kgr >> 3, kphys = kgr & 7;
    const int klog = kphys ^ (krow & 7);
    const int kLocal = krow * 2 + (klog >> 2);
    const ushort* ksrc = KTh + (size_t)kLocal * 32 + (klog & 3) * 8;

    gld16(vsrc,            &Vs[0][wid * 1024]);
    gld16(vsrc + 8 * 1024, &Vs[0][wid * 1024 + 512]);
    gld16(ksrc,            &Ks[0][wid * 512]);
    __syncthreads();

    f32x4 acc[4][4];   // [mf][qf]
    #pragma unroll
    for (int mf = 0; mf < 4; ++mf)
        #pragma unroll
        for (int qf = 0; qf < 4; ++qf) acc[mf][qf] = (f32x4){0.f, 0.f, 0.f, 0.f};
    float l_run[4] = {0.f, 0.f, 0.f, 0.f};
    const f32x4 zz = {0.f, 0.f, 0.f, 0.f};
    ushort* pt = &Pt[wid][0];

    for (int kt = 0; kt < 16; ++kt) {
        const int cur = kt & 1;
        if (kt < 15) {
            const int nxt = cur ^ 1;
            const int k0n = (kt + 1) * 64;
            gld16(vsrc + k0n,            &Vs[nxt][wid * 1024]);
            gld16(vsrc + k0n + 8 * 1024, &Vs[nxt][wid * 1024 + 512]);
            gld16(ksrc + k0n * 32,       &Ks[nxt][wid * 512]);
        }
        short8 kf[4];
        #pragma unroll
        for (int mf = 0; mf < 4; ++mf) {
            int k = mf * 16 + ln15;
            int row = k >> 1;
            int phys = ((k & 1) * 4 + g) ^ (row & 7);
            kf[mf] = *(const short8*)&Ks[cur][row * 64 + phys * 8];
        }

        #pragma unroll
        for (int qf = 0; qf < 4; ++qf) {
            f32x4 s[4];
            #pragma unroll
            for (int mf = 0; mf < 4; ++mf)
                s[mf] = __builtin_amdgcn_mfma_f32_16x16x32_bf16(kf[mf], qfr[qf], zz, 0, 0, 0);
            float lacc = 0.f;
            #pragma unroll
            for (int mf = 0; mf < 4; ++mf) {
                float p0 = __builtin_amdgcn_exp2f(s[mf][0]);
                float p1 = __builtin_amdgcn_exp2f(s[mf][1]);
                float p2 = __builtin_amdgcn_exp2f(s[mf][2]);
                float p3 = __builtin_amdgcn_exp2f(s[mf][3]);
                lacc += (p0 + p1) + (p2 + p3);
                union { ushort u[4]; uint2 v; } pk;
                pk.u[0] = f2bfu(p0); pk.u[1] = f2bfu(p1);
                pk.u[2] = f2bfu(p2); pk.u[3] = f2bfu(p3);
                *(uint2*)&pt[(qf * 16 + ln15) * 64 +
                             (((mf * 2 + (g >> 1)) ^ sw7) << 3) + (g & 1) * 4] = pk.v;
            }
            l_run[qf] += lacc;
        }

        #pragma unroll
        for (int ks = 0; ks < 2; ++ks) {
            short8 vf[4];
            #pragma unroll
            for (int mf = 0; mf < 4; ++mf)
                vf[mf] = *(const short8*)&Vs[cur][(mf * 16 + ln15) * 64 +
                                                  (((ks * 4 + g) ^ sw7) << 3)];
            #pragma unroll
            for (int qf = 0; qf < 4; ++qf) {
                short8 pf = *(const short8*)&pt[(qf * 16 + ln15) * 64 +
                                                (((ks * 4 + g) ^ sw7) << 3)];
                #pragma unroll
                for (int mf = 0; mf < 4; ++mf)
                    acc[mf][qf] = __builtin_amdgcn_mfma_f32_16x16x32_bf16(vf[mf], pf, acc[mf][qf], 0, 0, 0);
            }
        }
        __syncthreads();
    }

    #pragma unroll
    for (int qf = 0; qf < 4; ++qf) {
        float l = l_run[qf];
        l += __shfl_xor(l, 16);
        l += __shfl_xor(l, 32);
        float rl = 1.0f / l;
        const int lq = qw + qf * 16 + ln15;
        #pragma unroll
        for (int mf = 0; mf < 4; ++mf) {
            int dv = mf * 16 + g * 4;
            int c = h * 64 + dv;
            size_t base = ((size_t)(n * 1024 + c)) * 1024 + lq;
            union { ushort u[4]; uint2 v; } ph;
            #pragma unroll
            for (int r = 0; r < 4; ++r) {
                float val = acc[mf][qf][r] * rl + tokens[base + (size_t)r * 1024];
                ushort hh = f2bfu(val);
                ph.u[r] = hh;
                t2lo[base + (size_t)r * 1024] = f2bfu(val - bf2f(hh));
            }
            size_t tb = ((size_t)(n * 1024 + lq)) * 1024 + c;
            *(uint2*)&t2th[tb] = ph.v;
        }
    }
}

// ---------------- conv_f: single-product bf16 MFMA GEMM, BK=64, residual hi(LDS)+lo(global) ----
// grid (8 lblk, 8 coblk, NB), block 256 (4 waves 2x2). Tile 128co x 128l, 16 kt.
// LDS: As 2x16K + Xs 2x16K = 64K -> 2 blocks/CU.
// Row = 64 bf16 = 128B = 8 granules; phys granule = logical ^ (row&7); gld16 linear dest,
// pre-swizzled global source (rule #21). Residual-hi branch is wave-uniform with literal
// acc indices (rule #20 — round 4's scratch-spill bug).
__global__ __launch_bounds__(256, 2) void conv_f_mfma(
    const ushort* __restrict__ xh, const ushort* __restrict__ wh,
    const ushort* __restrict__ t2lo, const float* __restrict__ bf,
    float* __restrict__ out)
{
    __shared__ ushort As[2][128 * 64];
    __shared__ ushort Xs[2][128 * 64];
    const int l0 = blockIdx.x * 128, co0 = blockIdx.y * 128, n = blockIdx.z;
    const int tid = threadIdx.x;
    const int wid = tid >> 6, ln = tid & 63, g = ln >> 4, ln15 = ln & 15;
    const int wm = wid >> 1, wn = wid & 1;

    const ushort* srcA[4]; const ushort* srcX[4];
    #pragma unroll
    for (int j = 0; j < 4; ++j) {
        int g8 = wid * 64 + ln + j * 256;      // granule 0..1023 (16KB tile)
        int row = g8 >> 3, phys = g8 & 7;
        int logical = phys ^ (row & 7);
        srcA[j] = wh + (size_t)(co0 + row) * 1024 + logical * 8;
        srcX[j] = xh + ((size_t)(n * 1024 + l0 + row)) * 1024 + logical * 8;
    }

    f32x4 acc[4][4];
    #pragma unroll
    for (int mf = 0; mf < 4; ++mf)
        #pragma unroll
        for (int nf = 0; nf < 4; ++nf) acc[mf][nf] = (f32x4){0.f, 0.f, 0.f, 0.f};

    auto stage = [&](int k0, int b) {
        #pragma unroll
        for (int j = 0; j < 4; ++j) {
            gld16(srcA[j] + k0, &As[b][(j * 256 + wid * 64) * 8]);
            gld16(srcX[j] + k0, &Xs[b][(j * 256 + wid * 64) * 8]);
        }
    };

    stage(0, 0);
    __syncthreads();

    const int kt_res = (co0 >> 6) + wm;    // wave-uniform: this wave's co-range is kt_res*64..+64
    const int sub = (g & 1) * 4;

    for (int kt = 0; kt < 16; ++kt) {
        const int cur = kt & 1;
        if (kt < 15) stage((kt + 1) * 64, cur ^ 1);

        #pragma unroll
        for (int ks = 0; ks < 2; ++ks) {
            short8 a[4], b[4];
            #pragma unroll
            for (int mf = 0; mf < 4; ++mf) {
                const int row = wm * 64 + mf * 16 + ln15;
                a[mf] = *(const short8*)&As[cur][row * 64 + (((ks * 4 + g) ^ (row & 7)) << 3)];
            }
            #pragma unroll
            for (int nf = 0; nf < 4; ++nf) {
                const int row = wn * 64 + nf * 16 + ln15;
                b[nf] = *(const short8*)&Xs[cur][row * 64 + (((ks * 4 + g) ^ (row & 7)) << 3)];
            }
            #pragma unroll
            for (int mf = 0; mf < 4; ++mf)
                #pragma unroll
                for (int nf = 0; nf < 4; ++nf)
                    acc[mf][nf] = __builtin_amdgcn_mfma_f32_16x16x32_bf16(a[mf], b[nf], acc[mf][nf], 0, 0, 0);
        }

        // residual t2-hi: co range [kt*64, kt*64+64) is in Xs[cur]; ci = mf*16+g*4+r
        if (kt == kt_res) {
            #pragma unroll
            for (int mf = 0; mf < 4; ++mf) {
                const int ciG = 2 * mf + (g >> 1);
                #pragma unroll
                for (int nf = 0; nf < 4; ++nf) {
                    const int row = wn * 64 + nf * 16 + ln15;
                    const ushort* ph_ = &Xs[cur][row * 64 + ((ciG ^ (row & 7)) << 3) + sub];
                    #pragma unroll
                    for (int r = 0; r < 4; ++r)
                        acc[mf][nf][r] += bf2f(ph_[r]);
                }
            }
        }
        __syncthreads();
    }

    #pragma unroll
    for (int mf = 0; mf < 4; ++mf) {
        int co = co0 + wm * 64 + mf * 16 + g * 4;
        #pragma unroll
        for (int r = 0; r < 4; ++r) {
            float bb = bf[co + r];
            #pragma unroll
            for (int nf = 0; nf < 4; ++nf) {
                int l = l0 + wn * 64 + nf * 16 + ln15;
                size_t off = ((size_t)(n * 1024 + co + r)) * 1024 + l;
                out[off] = acc[mf][nf][r] + bb + bf2f(t2lo[off]);
            }
        }
    }
}

// ---------------- launch ----------------
extern "C" void kernel_launch(void* const* d_in, const int* in_sizes, int n_in,
                              void* d_out, int out_size, void* d_ws, size_t ws_size,
                              hipStream_t stream) {
    const float* tokens = (const float*)d_in[0];
    const float* kw  = (const float*)d_in[1];
    const float* kb_ = (const float*)d_in[2];
    const float* kg  = (const float*)d_in[3];
    const float* kbe = (const float*)d_in[4];
    const float* km  = (const float*)d_in[5];
    const float* kv  = (const float*)d_in[6];
    const float* qw  = (const float*)d_in[7];
    const float* qb_ = (const float*)d_in[8];
    const float* qg  = (const float*)d_in[9];
    const float* qbe = (const float*)d_in[10];
    const float* qm  = (const float*)d_in[11];
    const float* qv  = (const float*)d_in[12];
    const float* vw  = (const float*)d_in[13];
    const float* vb_ = (const float*)d_in[14];
    const float* vg  = (const float*)d_in[15];
    const float* vbe = (const float*)d_in[16];
    const float* vm  = (const float*)d_in[17];
    const float* vv  = (const float*)d_in[18];
    const float* fw  = (const float*)d_in[19];
    const float* fb_ = (const float*)d_in[20];
    const float* fg  = (const float*)d_in[21];
    const float* fbe = (const float*)d_in[22];
    const float* fm  = (const float*)d_in[23];
    const float* fv  = (const float*)d_in[24];

    char* ws = (char*)d_ws;
    ushort* WKQV = (ushort*)(ws + O_WKQV);
    float*  BKQV = (float*)(ws + O_BKQV);
    ushort* WFH  = (ushort*)(ws + O_WFH);
    float*  BF   = (float*)(ws + O_BF);
    ushort* TOKT = (ushort*)(ws + O_TOKT);   // tokensT, later t2T_hi
    ushort* T2LO = (ushort*)(ws + O_T2LO);
    ushort* KT   = (ushort*)(ws + O_KT);
    ushort* QT   = (ushort*)(ws + O_QT);
    ushort* Vb   = (ushort*)(ws + O_V);
    float*  out  = (float*)d_out;

    prep_all<<<5120, 256, 0, stream>>>(kw, kb_, kg, kbe, km, kv,
                                       qw, qb_, qg, qbe, qm, qv,
                                       vw, vb_, vg, vbe, vm, vv,
                                       fw, fb_, fg, fbe, fm, fv,
                                       WKQV, BKQV, WFH, BF);
    transpose_tokens<<<dim3(16, 16, NB), 256, 0, stream>>>(tokens, TOKT);
    conv_kqv_mfma<<<dim3(8, 32, NB), 256, 0, stream>>>(TOKT, WKQV, BKQV, KT, QT, Vb);
    attn_mfma<<<dim3(4, 16, NB), 256, 0, stream>>>(KT, QT, Vb, tokens, TOKT, T2LO);
    conv_f_mfma<<<dim3(8, 8, NB), 256, 0, stream>>>(TOKT, WFH, T2LO, BF, out);
}